// Round 1
// baseline (140.819 us; speedup 1.0000x reference)
//
#include <hip/hip_runtime.h>

// LatticeFilter: step-up (Levinson-Durbin) recursion, rc -> LPC coeffs.
//   rc: (B=16, p=128, Tf=8192) fp32, k_i = 0.98*rc[b,i,t]
//   out: (B, Tf, p+1=129) fp32, a[...,0]=1
// One thread per (b,t) column; 129-coeff state in registers; recursion fully
// unrolled so all register indices are static (no scratch). Step m:
//   a[m] = k           (a[0] is always 1)
//   pairs (j, m-j), j<m/2: both read old values -> tmp-swap fma
//   m even: a[m/2] += k*a[m/2]
// Epilogue: LDS transpose (row stride 129 -> linear read phase, conflict-free;
// write phase stride-129 = 2-way bank alias = free) then coalesced float4
// stores of a contiguous 33 KB region per round.

#define NB    16
#define ORD   128
#define TF    8192

__global__ __launch_bounds__(256, 2)
void lpc_stepup_kernel(const float* __restrict__ rc, float* __restrict__ out) {
    const int tid = threadIdx.x;
    const int gid = blockIdx.x * 256 + tid;   // row index in flattened (B*Tf)
    const int b = gid >> 13;                  // gid / TF
    const int t = gid & (TF - 1);             // gid % TF

    const float* rcp = rc + ((size_t)b * ORD) * TF + t;

    float a[ORD + 1];
    a[0] = 1.0f;

#pragma unroll
    for (int m = 1; m <= ORD; ++m) {
        const float k = 0.98f * rcp[(size_t)(m - 1) * TF];
#pragma unroll
        for (int j = 1; 2 * j < m; ++j) {
            const float lo = a[j];
            const float hi = a[m - j];
            a[j]     = fmaf(k, hi, lo);
            a[m - j] = fmaf(k, lo, hi);
        }
        if ((m & 1) == 0) {
            const float mid = a[m >> 1];
            a[m >> 1] = fmaf(k, mid, mid);
        }
        a[m] = k;
    }

    // ---- epilogue: transpose 256 rows x 129 cols through LDS, 4 rounds ----
    __shared__ __align__(16) float lds[64 * (ORD + 1)];   // 33,024 B
    const int my_round = tid >> 6;    // wave index (wave64) — uniform branch
    const int row      = tid & 63;
    float* out_block = out + (size_t)blockIdx.x * 256 * (ORD + 1);

    for (int r = 0; r < 4; ++r) {
        __syncthreads();
        if (my_round == r) {
#pragma unroll
            for (int j = 0; j <= ORD; ++j)
                lds[row * (ORD + 1) + j] = a[j];   // bank stride 1 -> free 2-way
        }
        __syncthreads();
        // 64 rows * 129 floats = 8256 floats = 2064 float4, contiguous in global
        const float4* lds4 = (const float4*)lds;
        float4* out4 = (float4*)(out_block + (size_t)r * 64 * (ORD + 1));
        for (int e = tid; e < (64 * (ORD + 1)) / 4; e += 256)
            out4[e] = lds4[e];                      // perfectly coalesced
    }
}

extern "C" void kernel_launch(void* const* d_in, const int* in_sizes, int n_in,
                              void* d_out, int out_size, void* d_ws, size_t ws_size,
                              hipStream_t stream) {
    // d_in[0] = excitation (dead in reference), d_in[1] = rc
    const float* rc = (const float*)d_in[1];
    float* out = (float*)d_out;
    dim3 grid((NB * TF) / 256);
    dim3 block(256);
    hipLaunchKernelGGL(lpc_stepup_kernel, grid, block, 0, stream, rc, out);
}